// Round 11
// baseline (405.855 us; speedup 1.0000x reference)
//
#include <hip/hip_runtime.h>
#include <stdint.h>

#define NEG_SLOPE 0.01f
#define HPG 32        // heads per k4 block
#define BSH 8         // head-bucket shift: bucket = head >> 8 (256 heads)
#define NBMAX 512     // max buckets (N=100K -> 391)
#define K1CH 8192     // edges per kA binning block (>=16 recs/segment)
#define CAP2 8192     // per-bucket staging capacity (avg ~3200)

typedef float f32x4 __attribute__((ext_vector_type(4)));
typedef short short8 __attribute__((ext_vector_type(8)));
typedef unsigned int u32;

// DPP butterfly adds (VALU): 0xB1 quad_perm xor1, 0x4E quad_perm xor2,
// 0x141 row_half_mirror, 0x128 row_ror:8 (xor-8 within the 16-lane row).
#define DPPADD(v, ctrl) ((v) + __int_as_float(__builtin_amdgcn_update_dpp( \
        0, __float_as_int(v), (ctrl), 0xF, 0xF, true)))

__device__ inline short f2bf(float f) {
    union { float f; uint32_t u; } x; x.f = f;
    uint32_t r = x.u + 0x7FFF + ((x.u >> 16) & 1);   // RNE
    return (short)(r >> 16);
}
__device__ inline float bf2f(unsigned short u) {
    union { uint32_t u; float f; } x; x.u = ((uint32_t)u) << 16; return x.f;
}

// ---- kA: fused {bucket-major edge bin} + {ego cvt + W^T pack} --------------
// (byte-identical to the round-8 version that measured 186.8us total)
__global__ void __launch_bounds__(512) kA(
        const int* __restrict__ head, const int* __restrict__ tail,
        const int* __restrict__ etype, int E, int NB, int nblk,
        u32* __restrict__ staging, int* bucket_cur,
        const float* __restrict__ ego, unsigned short* __restrict__ ego_bf,
        int NE8, const float* __restrict__ rw, short* __restrict__ wfrag,
        int* __restrict__ head_off, int N) {
    int t = threadIdx.x;
    int bid = blockIdx.x;
    if (bid < nblk) {
        __shared__ int lcnt[NBMAX], lbase[NBMAX], lfill[NBMAX];
        for (int b = t; b < NBMAX; b += 512) lcnt[b] = 0;
        __syncthreads();
        long long base = (long long)bid * K1CH;
        #pragma unroll
        for (int s = 0; s < K1CH / 512; ++s) {       // pass 1: count
            long long e = base + t + s * 512;
            if (e < E) atomicAdd(&lcnt[head[e] >> BSH], 1);
        }
        __syncthreads();
        for (int b = t; b < NB; b += 512) {          // one reservation/bucket
            int c = lcnt[b];
            lbase[b] = c ? atomicAdd(&bucket_cur[b], c) : 0;
            lfill[b] = 0;
        }
        __syncthreads();
        #pragma unroll
        for (int s = 0; s < K1CH / 512; ++s) {       // pass 2: place
            long long e = base + t + s * 512;
            if (e < E) {
                int h = head[e];
                int bk = h >> BSH;
                int rk = atomicAdd(&lfill[bk], 1);
                int pos = lbase[bk] + rk;
                if (pos >= CAP2) pos = CAP2 - 1;     // defensive clamp
                staging[(size_t)bk * CAP2 + pos] =
                    (u32)tail[e] | ((u32)etype[e] << 20) | ((u32)(h & 255) << 24);
            }
        }
    } else {
        int ib = bid - nblk;
        if (ib == 0 && t == 0) head_off[N] = E;
        if (ib < 16) {                               // W^T frag pack, r = ib
            int r = ib;
            int lane = t & 63;
            int c = lane & 15, q = lane >> 4;
            int pair = t >> 6;                       // 8 waves -> 8 pairs
            int t4 = pair >> 1, kh = pair & 1;
            int m = t4 * 16 + c;
            short8 f;
            for (int j = 0; j < 8; ++j) {
                int k = kh * 32 + q * 8 + j;
                f[j] = f2bf(rw[r * 4096 + k * 64 + m]);
            }
            *(short8*)(wfrag + ((size_t)((r * 4 + t4) * 2 + kh) * 64 + lane) * 8) = f;
        }
        int i = ib * 512 + t;
        if (i < NE8) {
            const float4* p = (const float4*)ego + (size_t)i * 2;
            float4 a = p[0], b = p[1];
            short8 v;
            v[0] = f2bf(a.x); v[1] = f2bf(a.y); v[2] = f2bf(a.z); v[3] = f2bf(a.w);
            v[4] = f2bf(b.x); v[5] = f2bf(b.y); v[6] = f2bf(b.z); v[7] = f2bf(b.w);
            *(short8*)(ego_bf + (size_t)i * 8) = v;
        }
    }
}

// ---- kB: per-bucket count + scan + head_off + head-sorted place ------------
// (byte-identical to the round-8 version)
__global__ void __launch_bounds__(512) kB(
        const u32* __restrict__ staging, const int* __restrict__ bucket_cur,
        int* __restrict__ head_off, int* __restrict__ recs2, int N, int NB) {
    __shared__ int pre[NBMAX];
    __shared__ int lcnt[256], lofs[256], lfill[256];
    __shared__ u32 lrec[CAP2];
    int t = threadIdx.x;
    int b = blockIdx.x;
    if (t < 256) lcnt[t] = 0;
    int v = (t < NB) ? bucket_cur[t] : 0;
    pre[t] = v;
    __syncthreads();
    for (int off = 1; off < 512; off <<= 1) {        // inclusive scan
        int x = (t >= off) ? pre[t - off] : 0;
        __syncthreads();
        pre[t] += x;
        __syncthreads();
    }
    int cnt_raw = bucket_cur[b];
    int base_g = pre[b] - cnt_raw;                   // exclusive prefix
    int cntb = cnt_raw > CAP2 ? CAP2 : cnt_raw;
    int hbase = b << BSH;
    const u32* sb = staging + (size_t)b * CAP2;
    for (int t0 = t; t0 < cntb; t0 += 512) {         // phase A: cache + count
        u32 rec = sb[t0];
        lrec[t0] = rec;
        atomicAdd(&lcnt[rec >> 24], 1);
    }
    __syncthreads();
    if (t < 64) {                                    // scan 256 counters
        int cl[4]; int cs = 0;
        #pragma unroll
        for (int j = 0; j < 4; ++j) { cl[j] = lcnt[t * 4 + j]; cs += cl[j]; }
        int inc = cs;
        for (int off = 1; off < 64; off <<= 1) {
            int u = __shfl_up(inc, off);
            if (t >= off) inc += u;
        }
        int run = inc - cs;
        #pragma unroll
        for (int j = 0; j < 4; ++j) {
            lofs[t * 4 + j] = run; lfill[t * 4 + j] = run; run += cl[j];
        }
    }
    __syncthreads();
    if (t < 256 && hbase + t < N)                    // this bucket's head_off
        head_off[hbase + t] = base_g + lofs[t];
    for (int t0 = t; t0 < cntb; t0 += 512) {         // phase B: place
        u32 rec = lrec[t0];
        int rk = atomicAdd(&lfill[rec >> 24], 1);
        recs2[base_g + rk] = (int)(rec & 0xFFFFFF);
    }
}

// ---- K4: 1024-thread, 32-waves/CU version ---------------------------------
// T uses XOR-swizzled 16B chunks (row stride 64 halfwords, chunk ^= row&7):
// same bank spread as the old +8 pad, 8KB less LDS -> T+cmb fit 2 blocks/CU.
// Phase 1: wave w computes type w for all 32 heads (16 waves = 16 types).
// Phase 2: each head gets TWO quarters (waves 0-7: first half of edge list,
// waves 8-15: second half); halves combine through the cmb LDS buffer.
__global__ void __launch_bounds__(1024, 8) k4_fused(
        const unsigned short* __restrict__ ego_bf,
        const short* __restrict__ wfrag,
        const int* __restrict__ recs2,
        const int* __restrict__ head_off,
        float* __restrict__ out, int N) {
    __shared__ unsigned short T[16 * HPG * 64];     // 65,536 B (swizzled)
    __shared__ float cmb[HPG][8][9];                // 9,216 B
    int tid = threadIdx.x;
    int wave = tid >> 6;                            // 0..15
    int lane = tid & 63;
    int c = lane & 15, q = lane >> 4;
    int hb = blockIdx.x * HPG;

    // ---------------- phase 1: wave = type, 32 heads ----------------------
    {
        int r = wave;
        const short* wp = wfrag + (size_t)r * 4096;
        short8 wf[4][2];
        #pragma unroll
        for (int t4 = 0; t4 < 4; ++t4)
            #pragma unroll
            for (int kh = 0; kh < 2; ++kh)
                wf[t4][kh] = *(const short8*)(wp + ((size_t)((t4 * 2 + kh) * 64 + lane)) * 8);
        #pragma unroll
        for (int hf = 0; hf < 2; ++hf) {
            int hrow = hb + hf * 16 + c;
            if (hrow >= N) hrow = N - 1;           // clamp; garbage T never read
            const unsigned short* hr = ego_bf + (size_t)hrow * 64;
            short8 b0 = *(const short8*)(hr + q * 8);
            short8 b1 = *(const short8*)(hr + 32 + q * 8);
            int row = r * HPG + hf * 16 + c;
            #pragma unroll
            for (int t4 = 0; t4 < 4; ++t4) {
                f32x4 a = {0.f, 0.f, 0.f, 0.f};
                a = __builtin_amdgcn_mfma_f32_16x16x32_bf16(wf[t4][0], b0, a, 0, 0, 0);
                a = __builtin_amdgcn_mfma_f32_16x16x32_bf16(wf[t4][1], b1, a, 0, 0, 0);
                ushort4 us;
                us.x = (unsigned short)f2bf(a[0]);
                us.y = (unsigned short)f2bf(a[1]);
                us.z = (unsigned short)f2bf(a[2]);
                us.w = (unsigned short)f2bf(a[3]);
                int chunk = t4 * 2 + (q >> 1);      // 16B chunk index 0..7
                int ha = row * 64 + ((chunk ^ (row & 7)) * 8) + (q & 1) * 4;
                *(ushort4*)&T[ha] = us;
            }
        }
    }
    __syncthreads();

    // ---------------- phase 2: two quarters per head ----------------------
    int hql = (wave & 7) * 4 + q;                   // head-in-block 0..31
    int halfsel = wave >> 3;                        // 0: front half, 1: back
    int h = hb + hql;
    bool act = (h < N);
    int lq = c;                                     // lane within quarter
    int g2 = lq >> 3, c8 = lq & 7;
    int qb = q * 16;
    int s0g = 0, cntF = 0;
    if (act) { s0g = head_off[h]; cntF = head_off[h + 1] - s0g; }
    int m = cntF >> 1;
    int a0 = s0g + (halfsel ? m : 0);
    int cnt = halfsel ? (cntF - m) : m;
    int nbt = (cnt + 15) >> 4;
    float acc[8] = {0.f, 0.f, 0.f, 0.f, 0.f, 0.f, 0.f, 0.f};
    float den = 0.f;

    auto loadRec = [&](int b) -> int {              // coalesced 4B/lane load
        if (b >= nbt) return 0;
        int idx = b * 16 + lq;
        return (idx < cnt) ? recs2[a0 + idx] : 0;
    };

    int rjA[8]; short8 rowsA[8];
    int recL1;
    {
        int recL0 = loadRec(0);
        #pragma unroll
        for (int j = 0; j < 8; ++j) rjA[j] = __shfl(recL0, qb + j * 2 + g2);
        #pragma unroll
        for (int j = 0; j < 8; ++j)
            rowsA[j] = *(const short8*)(ego_bf + (size_t)(rjA[j] & 0xFFFFF) * 64 + c8 * 8);
        recL1 = loadRec(1);
    }
    for (int b = 0; b < nbt; ++b) {
        int recL2 = loadRec(b + 2);                 // S(b+2)
        int rjB[8]; short8 rowsB[8];
        #pragma unroll
        for (int j = 0; j < 8; ++j) rjB[j] = __shfl(recL1, qb + j * 2 + g2);
        #pragma unroll
        for (int j = 0; j < 8; ++j)                 // G(b+1) in flight over C(b)
            rowsB[j] = *(const short8*)(ego_bf + (size_t)(rjB[j] & 0xFFFFF) * 64 + c8 * 8);
        int ng = cnt - b * 16; if (ng > 16) ng = 16;
        #pragma unroll
        for (int sIt = 0; sIt < 8; ++sIt) {         // C(b)
            if (sIt * 2 < ng) {
                int row2 = ((rjA[sIt] >> 20) & 15) * HPG + hql;
                int ha = row2 * 64 + ((c8 ^ (row2 & 7)) * 8);
                short8 trw = *(const short8*)&T[ha];
                float rf[8];
                float sa = 0.f, sb2 = 0.f;
                #pragma unroll
                for (int k = 0; k < 4; ++k) {
                    rf[k] = bf2f((unsigned short)rowsA[sIt][k]);
                    sa += rf[k] * bf2f((unsigned short)trw[k]);
                }
                #pragma unroll
                for (int k = 4; k < 8; ++k) {
                    rf[k] = bf2f((unsigned short)rowsA[sIt][k]);
                    sb2 += rf[k] * bf2f((unsigned short)trw[k]);
                }
                float s = sa + sb2;
                s = DPPADD(s, 0xB1);                // xor1
                s = DPPADD(s, 0x4E);                // xor2
                s = DPPADD(s, 0x141);               // other quad
                float lr = s > 0.f ? s : NEG_SLOPE * s;
                float w = (sIt * 2 + g2 < ng) ? __expf(lr) : 0.f;
                den += w;
                #pragma unroll
                for (int k = 0; k < 8; ++k) acc[k] += w * rf[k];
            }
        }
        recL1 = recL2;
        #pragma unroll
        for (int j = 0; j < 8; ++j) { rjA[j] = rjB[j]; rowsA[j] = rowsB[j]; }
    }
    den = DPPADD(den, 0x128);                       // combine 2 edge slots
    #pragma unroll
    for (int k = 0; k < 8; ++k) acc[k] = DPPADD(acc[k], 0x128);

    if (halfsel && g2 == 0) {                       // back half -> LDS
        #pragma unroll
        for (int k = 0; k < 8; ++k) cmb[hql][c8][k] = acc[k];
        cmb[hql][c8][8] = den;
    }
    __syncthreads();
    if (!halfsel && g2 == 0 && act) {               // front half combines+stores
        #pragma unroll
        for (int k = 0; k < 8; ++k) acc[k] += cmb[hql][c8][k];
        den += cmb[hql][c8][8];
        float sc = (cntF > 0) ? 1.f / (den * (float)cntF) : 0.f;
        float4 v0 = {acc[0] * sc, acc[1] * sc, acc[2] * sc, acc[3] * sc};
        float4 v1 = {acc[4] * sc, acc[5] * sc, acc[6] * sc, acc[7] * sc};
        float* op = out + (size_t)h * 64 + c8 * 8;
        *(float4*)op = v0;
        *(float4*)(op + 4) = v1;
    }
}

extern "C" void kernel_launch(void* const* d_in, const int* in_sizes, int n_in,
                              void* d_out, int out_size, void* d_ws, size_t ws_size,
                              hipStream_t stream) {
    const float* ego = (const float*)d_in[0];
    const float* rw  = (const float*)d_in[1];
    const int* eidx  = (const int*)d_in[2];
    const int* etyp  = (const int*)d_in[3];
    int N = in_sizes[0] / 64;
    int E = in_sizes[3];
    const int* head = eidx;
    const int* tail = eidx + E;
    float* out = (float*)d_out;

    char* ws = (char*)d_ws;
    size_t o = 0;
    auto take = [&](size_t bytes) -> char* {
        char* p = ws + o;
        o = (o + bytes + 255) & ~(size_t)255;
        return p;
    };
    int NB = (N + (1 << BSH) - 1) >> BSH;
    if (NB > NBMAX) NB = NBMAX;            // defensive; N=100K -> 391
    int nblk = (E + K1CH - 1) / K1CH;      // 1.25M -> 153
    int NE8 = N * 8;
    int nbI = (NE8 + 511) / 512;           // init blocks (>= 16 for W pack)
    if (nbI < 16) nbI = 16;
    unsigned short* ego_bf = (unsigned short*)take((size_t)N * 64 * 2);
    short* wfrag    = (short*)take(16 * 4096 * 2);
    int* recs2      = (int*)take((size_t)E * 4);
    u32* staging    = (u32*)take((size_t)NB * CAP2 * 4);
    int* bucket_cur = (int*)take(NBMAX * 4);
    int* head_off   = (int*)take((size_t)(N + 1) * 4);
    (void)ws_size; (void)n_in; (void)out_size;

    hipMemsetAsync(bucket_cur, 0, NBMAX * 4, stream);
    kA<<<nblk + nbI, 512, 0, stream>>>(head, tail, etyp, E, NB, nblk,
                                       staging, bucket_cur,
                                       ego, ego_bf, NE8, rw, wfrag,
                                       head_off, N);
    kB<<<NB, 512, 0, stream>>>(staging, bucket_cur, head_off, recs2, N, NB);
    k4_fused<<<(N + HPG - 1) / HPG, 1024, 0, stream>>>(ego_bf, wfrag, recs2,
                                                       head_off, out, N);
}

// Round 12
// 180.021 us; speedup vs baseline: 2.2545x; 2.2545x over previous
//
#include <hip/hip_runtime.h>
#include <stdint.h>

#define NEG_SLOPE 0.01f
#define HPG 32        // heads per k4 block
#define TSTR 72       // padded T row stride (halfwords)
#define BSH 8         // head-bucket shift: bucket = head >> 8 (256 heads)
#define NBMAX 512     // max buckets (N=100K -> 391)
#define K1CH 8192     // edges per kA binning block (~21 recs/segment)
#define CAP2 8192     // per-bucket staging capacity (avg ~3200)

typedef float f32x4 __attribute__((ext_vector_type(4)));
typedef short short8 __attribute__((ext_vector_type(8)));
typedef unsigned int u32;

// DPP butterfly adds (VALU): 0xB1 quad_perm xor1, 0x4E quad_perm xor2,
// 0x141 row_half_mirror, 0x128 row_ror:8 (xor-8 within the 16-lane row).
#define DPPADD(v, ctrl) ((v) + __int_as_float(__builtin_amdgcn_update_dpp( \
        0, __float_as_int(v), (ctrl), 0xF, 0xF, true)))

__device__ inline short f2bf(float f) {
    union { float f; uint32_t u; } x; x.f = f;
    uint32_t r = x.u + 0x7FFF + ((x.u >> 16) & 1);   // RNE
    return (short)(r >> 16);
}
__device__ inline float bf2f(unsigned short u) {
    union { uint32_t u; float f; } x; x.u = ((uint32_t)u) << 16; return x.f;
}

// ---- kA: fused {bucket-major edge bin} + {ego cvt + W^T pack} --------------
// Binning: pass 1 reads head/tail/etype ONCE, counts per bucket in LDS and
// keeps the packed record in registers; one global reservation atomic per
// (block,bucket); pass 2 places from registers (zero global reads).
__global__ void __launch_bounds__(512) kA(
        const int* __restrict__ head, const int* __restrict__ tail,
        const int* __restrict__ etype, int E, int NB, int nblk,
        u32* __restrict__ staging, int* bucket_cur,
        const float* __restrict__ ego, unsigned short* __restrict__ ego_bf,
        int NE8, const float* __restrict__ rw, short* __restrict__ wfrag,
        int* __restrict__ head_off, int N) {
    int t = threadIdx.x;
    int bid = blockIdx.x;
    if (bid < nblk) {
        __shared__ int lcnt[NBMAX], lbase[NBMAX], lfill[NBMAX];
        for (int b = t; b < NBMAX; b += 512) lcnt[b] = 0;
        __syncthreads();
        long long base = (long long)bid * K1CH;
        short mybk[K1CH / 512];                      // bucket (or -1)
        u32 myrec[K1CH / 512];                       // packed record
        #pragma unroll
        for (int s = 0; s < K1CH / 512; ++s) {       // pass 1: read+count+save
            long long e = base + t + s * 512;
            int bk = -1; u32 rec = 0;
            if (e < E) {
                int h = head[e];
                bk = h >> BSH;
                rec = (u32)tail[e] | ((u32)etype[e] << 20) | ((u32)(h & 255) << 24);
                atomicAdd(&lcnt[bk], 1);
            }
            mybk[s] = (short)bk; myrec[s] = rec;
        }
        __syncthreads();
        for (int b = t; b < NB; b += 512) {          // one reservation/bucket
            int c = lcnt[b];
            lbase[b] = c ? atomicAdd(&bucket_cur[b], c) : 0;
            lfill[b] = 0;
        }
        __syncthreads();
        #pragma unroll
        for (int s = 0; s < K1CH / 512; ++s) {       // pass 2: place (reg-fed)
            int bk = mybk[s];
            if (bk >= 0) {
                int rk = atomicAdd(&lfill[bk], 1);
                int pos = lbase[bk] + rk;
                if (pos >= CAP2) pos = CAP2 - 1;     // defensive clamp
                staging[(size_t)bk * CAP2 + pos] = myrec[s];
            }
        }
    } else {
        int ib = bid - nblk;
        if (ib == 0 && t == 0) head_off[N] = E;
        if (ib < 16) {                               // W^T frag pack, r = ib
            int r = ib;
            int lane = t & 63;
            int c = lane & 15, q = lane >> 4;
            int pair = t >> 6;                       // 8 waves -> 8 pairs
            int t4 = pair >> 1, kh = pair & 1;
            int m = t4 * 16 + c;
            short8 f;
            for (int j = 0; j < 8; ++j) {
                int k = kh * 32 + q * 8 + j;
                f[j] = f2bf(rw[r * 4096 + k * 64 + m]);
            }
            *(short8*)(wfrag + ((size_t)((r * 4 + t4) * 2 + kh) * 64 + lane) * 8) = f;
        }
        int i = ib * 512 + t;
        if (i < NE8) {
            const float4* p = (const float4*)ego + (size_t)i * 2;
            float4 a = p[0], b = p[1];
            short8 v;
            v[0] = f2bf(a.x); v[1] = f2bf(a.y); v[2] = f2bf(a.z); v[3] = f2bf(a.w);
            v[4] = f2bf(b.x); v[5] = f2bf(b.y); v[6] = f2bf(b.z); v[7] = f2bf(b.w);
            *(short8*)(ego_bf + (size_t)i * 8) = v;
        }
    }
}

// ---- kB: per-bucket count + scan + head_off + head-sorted place ------------
// (byte-identical to the round-8 version)
__global__ void __launch_bounds__(512) kB(
        const u32* __restrict__ staging, const int* __restrict__ bucket_cur,
        int* __restrict__ head_off, int* __restrict__ recs2, int N, int NB) {
    __shared__ int pre[NBMAX];
    __shared__ int lcnt[256], lofs[256], lfill[256];
    __shared__ u32 lrec[CAP2];
    int t = threadIdx.x;
    int b = blockIdx.x;
    if (t < 256) lcnt[t] = 0;
    int v = (t < NB) ? bucket_cur[t] : 0;
    pre[t] = v;
    __syncthreads();
    for (int off = 1; off < 512; off <<= 1) {        // inclusive scan
        int x = (t >= off) ? pre[t - off] : 0;
        __syncthreads();
        pre[t] += x;
        __syncthreads();
    }
    int cnt_raw = bucket_cur[b];
    int base_g = pre[b] - cnt_raw;                   // exclusive prefix
    int cntb = cnt_raw > CAP2 ? CAP2 : cnt_raw;
    int hbase = b << BSH;
    const u32* sb = staging + (size_t)b * CAP2;
    for (int t0 = t; t0 < cntb; t0 += 512) {         // phase A: cache + count
        u32 rec = sb[t0];
        lrec[t0] = rec;
        atomicAdd(&lcnt[rec >> 24], 1);
    }
    __syncthreads();
    if (t < 64) {                                    // scan 256 counters
        int cl[4]; int cs = 0;
        #pragma unroll
        for (int j = 0; j < 4; ++j) { cl[j] = lcnt[t * 4 + j]; cs += cl[j]; }
        int inc = cs;
        for (int off = 1; off < 64; off <<= 1) {
            int u = __shfl_up(inc, off);
            if (t >= off) inc += u;
        }
        int run = inc - cs;
        #pragma unroll
        for (int j = 0; j < 4; ++j) {
            lofs[t * 4 + j] = run; lfill[t * 4 + j] = run; run += cl[j];
        }
    }
    __syncthreads();
    if (t < 256 && hbase + t < N)                    // this bucket's head_off
        head_off[hbase + t] = base_g + lofs[t];
    for (int t0 = t; t0 < cntb; t0 += 512) {         // phase B: place
        u32 rec = lrec[t0];
        int rk = atomicAdd(&lfill[rec >> 24], 1);
        recs2[base_g + rk] = (int)(rec & 0xFFFFFF);
    }
}

// ---- K4: fused transform + score + softmax + aggregate ---------------------
// (byte-identical to the round-8 version that measured 75.7us)
__global__ void __launch_bounds__(512, 4) k4_fused(
        const unsigned short* __restrict__ ego_bf,
        const short* __restrict__ wfrag,
        const int* __restrict__ recs2,
        const int* __restrict__ head_off,
        float* __restrict__ out, int N) {
    __shared__ unsigned short T[16 * HPG * TSTR];   // 73,728 B -> 2 blocks/CU
    int tid = threadIdx.x;
    int wave = tid >> 6;
    int lane = tid & 63;
    int c = lane & 15, q = lane >> 4;
    int hb = blockIdx.x * HPG;

    // ---------------- phase 1: per-wave 2 types x 32 heads ----------------
    for (int t = 0; t < 2; ++t) {
        int r = wave * 2 + t;
        const short* wp = wfrag + (size_t)r * 4096;
        short8 wf[4][2];
        #pragma unroll
        for (int t4 = 0; t4 < 4; ++t4)
            #pragma unroll
            for (int kh = 0; kh < 2; ++kh)
                wf[t4][kh] = *(const short8*)(wp + ((size_t)((t4 * 2 + kh) * 64 + lane)) * 8);
        #pragma unroll
        for (int hf = 0; hf < 2; ++hf) {
            int hrow = hb + hf * 16 + c;
            if (hrow >= N) hrow = N - 1;           // clamp; garbage T never read
            const unsigned short* hr = ego_bf + (size_t)hrow * 64;
            short8 b0 = *(const short8*)(hr + q * 8);
            short8 b1 = *(const short8*)(hr + 32 + q * 8);
            #pragma unroll
            for (int t4 = 0; t4 < 4; ++t4) {
                f32x4 a = {0.f, 0.f, 0.f, 0.f};
                a = __builtin_amdgcn_mfma_f32_16x16x32_bf16(wf[t4][0], b0, a, 0, 0, 0);
                a = __builtin_amdgcn_mfma_f32_16x16x32_bf16(wf[t4][1], b1, a, 0, 0, 0);
                ushort4 us;
                us.x = (unsigned short)f2bf(a[0]);
                us.y = (unsigned short)f2bf(a[1]);
                us.z = (unsigned short)f2bf(a[2]);
                us.w = (unsigned short)f2bf(a[3]);
                *(ushort4*)&T[(size_t)(r * HPG + hf * 16 + c) * TSTR + t4 * 16 + q * 4] = us;
            }
        }
    }
    __syncthreads();

    // ---------------- phase 2: quarter (wave,q) owns head hb + wave*4 + q --
    int hql = wave * 4 + q;
    int h = hb + hql;
    if (h >= N) return;
    int lq = c;                   // lane within quarter
    int g2 = lq >> 3, c8 = lq & 7;
    int qb = q * 16;
    int s0 = head_off[h], s1 = head_off[h + 1];
    int cnt = s1 - s0;
    int nbt = (cnt + 15) >> 4;
    float acc[8] = {0.f, 0.f, 0.f, 0.f, 0.f, 0.f, 0.f, 0.f};
    float den = 0.f;

    auto loadRec = [&](int b) -> int {             // one coalesced 4B/lane load
        if (b >= nbt) return 0;
        int idx = s0 + b * 16 + lq;
        return (idx < s1) ? recs2[idx] : 0;
    };

    int rjA[8]; short8 rowsA[8];
    int recL1;
    {
        int recL0 = loadRec(0);
        #pragma unroll
        for (int j = 0; j < 8; ++j) rjA[j] = __shfl(recL0, qb + j * 2 + g2);
        #pragma unroll
        for (int j = 0; j < 8; ++j)
            rowsA[j] = *(const short8*)(ego_bf + (size_t)(rjA[j] & 0xFFFFF) * 64 + c8 * 8);
        recL1 = loadRec(1);
    }
    for (int b = 0; b < nbt; ++b) {
        int recL2 = loadRec(b + 2);                // S(b+2)
        int rjB[8]; short8 rowsB[8];
        #pragma unroll
        for (int j = 0; j < 8; ++j) rjB[j] = __shfl(recL1, qb + j * 2 + g2);
        #pragma unroll
        for (int j = 0; j < 8; ++j)                // G(b+1): in flight across C(b)
            rowsB[j] = *(const short8*)(ego_bf + (size_t)(rjB[j] & 0xFFFFF) * 64 + c8 * 8);
        int ng = s1 - (s0 + b * 16); if (ng > 16) ng = 16;
        #pragma unroll
        for (int sIt = 0; sIt < 8; ++sIt) {        // C(b)
            if (sIt * 2 < ng) {
                short8 trw = *(const short8*)&T[(size_t)(((u32)rjA[sIt] >> 20) * HPG + hql) * TSTR + c8 * 8];
                float rf[8];
                float sa = 0.f, sb = 0.f;
                #pragma unroll
                for (int k = 0; k < 4; ++k) {
                    rf[k] = bf2f((unsigned short)rowsA[sIt][k]);
                    sa += rf[k] * bf2f((unsigned short)trw[k]);
                }
                #pragma unroll
                for (int k = 4; k < 8; ++k) {
                    rf[k] = bf2f((unsigned short)rowsA[sIt][k]);
                    sb += rf[k] * bf2f((unsigned short)trw[k]);
                }
                float s = sa + sb;
                s = DPPADD(s, 0xB1);               // xor1
                s = DPPADD(s, 0x4E);               // xor2
                s = DPPADD(s, 0x141);              // other quad
                float lr = s > 0.f ? s : NEG_SLOPE * s;
                float w = (sIt * 2 + g2 < ng) ? __expf(lr) : 0.f;
                den += w;
                #pragma unroll
                for (int k = 0; k < 8; ++k) acc[k] += w * rf[k];
            }
        }
        recL1 = recL2;
        #pragma unroll
        for (int j = 0; j < 8; ++j) { rjA[j] = rjB[j]; rowsA[j] = rowsB[j]; }
    }
    den = DPPADD(den, 0x128);                      // combine 2 edge slots
    #pragma unroll
    for (int k = 0; k < 8; ++k) acc[k] = DPPADD(acc[k], 0x128);
    if (g2 == 0) {
        float sc = (cnt > 0) ? 1.f / (den * (float)cnt) : 0.f;
        float4 v0 = {acc[0] * sc, acc[1] * sc, acc[2] * sc, acc[3] * sc};
        float4 v1 = {acc[4] * sc, acc[5] * sc, acc[6] * sc, acc[7] * sc};
        float* op = out + (size_t)h * 64 + c8 * 8;
        *(float4*)op = v0;
        *(float4*)(op + 4) = v1;
    }
}

extern "C" void kernel_launch(void* const* d_in, const int* in_sizes, int n_in,
                              void* d_out, int out_size, void* d_ws, size_t ws_size,
                              hipStream_t stream) {
    const float* ego = (const float*)d_in[0];
    const float* rw  = (const float*)d_in[1];
    const int* eidx  = (const int*)d_in[2];
    const int* etyp  = (const int*)d_in[3];
    int N = in_sizes[0] / 64;
    int E = in_sizes[3];
    const int* head = eidx;
    const int* tail = eidx + E;
    float* out = (float*)d_out;

    char* ws = (char*)d_ws;
    size_t o = 0;
    auto take = [&](size_t bytes) -> char* {
        char* p = ws + o;
        o = (o + bytes + 255) & ~(size_t)255;
        return p;
    };
    int NB = (N + (1 << BSH) - 1) >> BSH;
    if (NB > NBMAX) NB = NBMAX;            // defensive; N=100K -> 391
    int nblk = (E + K1CH - 1) / K1CH;      // 1.25M -> 153
    int NE8 = N * 8;
    int nbI = (NE8 + 511) / 512;           // init blocks (>= 16 for W pack)
    if (nbI < 16) nbI = 16;
    unsigned short* ego_bf = (unsigned short*)take((size_t)N * 64 * 2);
    short* wfrag    = (short*)take(16 * 4096 * 2);
    int* recs2      = (int*)take((size_t)E * 4);
    u32* staging    = (u32*)take((size_t)NB * CAP2 * 4);
    int* bucket_cur = (int*)take(NBMAX * 4);
    int* head_off   = (int*)take((size_t)(N + 1) * 4);
    (void)ws_size; (void)n_in; (void)out_size;

    hipMemsetAsync(bucket_cur, 0, NBMAX * 4, stream);
    kA<<<nblk + nbI, 512, 0, stream>>>(head, tail, etyp, E, NB, nblk,
                                       staging, bucket_cur,
                                       ego, ego_bf, NE8, rw, wfrag,
                                       head_off, N);
    kB<<<NB, 512, 0, stream>>>(staging, bucket_cur, head_off, recs2, N, NB);
    k4_fused<<<(N + HPG - 1) / HPG, 512, 0, stream>>>(ego_bf, wfrag, recs2,
                                                      head_off, out, N);
}